// Round 1
// baseline (674.809 us; speedup 1.0000x reference)
//
#include <hip/hip_runtime.h>

#define NEG 0.2f

// ---------------------------------------------------------------------------
// GEMM1: h1 = x @ W1  (N x 128) @ (128 x 128), fused alpha_src/alpha_dst
// block = 128 threads (2 waves). wave0 = head0 cols 0..63, wave1 = head1.
// Each block handles NB1 nodes; x reads are thread-uniform -> scalar loads.
// ---------------------------------------------------------------------------
constexpr int NB1 = 8;

__global__ __launch_bounds__(128) void gemm1_kernel(
    const float* __restrict__ x, const float* __restrict__ W,
    const float* __restrict__ a_src, const float* __restrict__ a_dst,
    float* __restrict__ h, float* __restrict__ asrc, float* __restrict__ adst,
    int N)
{
  const int j  = threadIdx.x;          // output column 0..127
  const int n0 = blockIdx.x * NB1;

  float acc[NB1];
#pragma unroll
  for (int n = 0; n < NB1; ++n) acc[n] = 0.f;

#pragma unroll 4
  for (int k = 0; k < 128; ++k) {
    float w = W[k * 128 + j];
#pragma unroll
    for (int n = 0; n < NB1; ++n) {
      int nn = n0 + n; if (nn >= N) nn = N - 1;   // clamp (N divisible by 8 anyway)
      acc[n] += x[(size_t)nn * 128 + k] * w;
    }
  }

  const float as = a_src[j];
  const float ad = a_dst[j];
  const int lane = j & 63;
  const int head = j >> 6;

#pragma unroll
  for (int n = 0; n < NB1; ++n) {
    const int nn = n0 + n;
    if (nn >= N) break;
    h[(size_t)nn * 128 + j] = acc[n];
    float vs = acc[n] * as;
    float vd = acc[n] * ad;
#pragma unroll
    for (int m = 32; m >= 1; m >>= 1) {
      vs += __shfl_xor(vs, m, 64);
      vd += __shfl_xor(vd, m, 64);
    }
    if (lane == 0) {
      asrc[nn * 2 + head] = vs;
      adst[nn * 2 + head] = vd;
    }
  }
}

// ---------------------------------------------------------------------------
// Edge aggregation layer 1: one 64-lane wave per edge (2 heads x 64 dims).
// acc[dst] += w_h * h[src], denom[dst][h] += w_h   (unnormalized; divide later)
// ---------------------------------------------------------------------------
__global__ __launch_bounds__(256) void edge1_kernel(
    const int* __restrict__ ei, const float* __restrict__ h,
    const float* __restrict__ asrc, const float* __restrict__ adst,
    float* __restrict__ acc, float* __restrict__ denom, int E, int N)
{
  const int wid  = (blockIdx.x * 256 + threadIdx.x) >> 6;
  const int lane = threadIdx.x & 63;
  if (wid >= E + N) return;

  int s, d;
  if (wid < E) { s = ei[wid]; d = ei[E + wid]; }
  else         { s = d = wid - E; }              // self-loop

  float e0 = asrc[2 * s]     + adst[2 * d];
  float e1 = asrc[2 * s + 1] + adst[2 * d + 1];
  e0 = e0 > 0.f ? e0 : NEG * e0;
  e1 = e1 > 0.f ? e1 : NEG * e1;
  const float w0 = expf(e0);
  const float w1 = expf(e1);

  if (lane == 0) atomicAdd(&denom[2 * d],     w0);
  if (lane == 1) atomicAdd(&denom[2 * d + 1], w1);

  const float v0 = h[(size_t)s * 128 + lane];
  const float v1 = h[(size_t)s * 128 + 64 + lane];
  atomicAdd(&acc[(size_t)d * 128 + lane],      w0 * v0);
  atomicAdd(&acc[(size_t)d * 128 + 64 + lane], w1 * v1);
}

// out1 = relu(acc/denom + b), written in place over acc
__global__ void norm1_kernel(float* __restrict__ acc,
                             const float* __restrict__ denom,
                             const float* __restrict__ b, int N)
{
  const int i = blockIdx.x * blockDim.x + threadIdx.x;
  if (i >= N * 128) return;
  const int n = i >> 7, j = i & 127;
  float v = acc[i] / denom[n * 2 + (j >> 6)] + b[j];
  acc[i] = v > 0.f ? v : 0.f;
}

// ---------------------------------------------------------------------------
// GEMM2: h2 = out1 @ W2  (N x 128) @ (128 x 32), fused alpha2 (single head)
// block = 256 threads = 8 nodes x 32 cols
// ---------------------------------------------------------------------------
constexpr int NB2 = 8;

__global__ __launch_bounds__(256) void gemm2_kernel(
    const float* __restrict__ x, const float* __restrict__ W,
    const float* __restrict__ a_src, const float* __restrict__ a_dst,
    float* __restrict__ h, float* __restrict__ asrc, float* __restrict__ adst,
    int N)
{
  const int t = threadIdx.x;
  const int c = t & 31;
  const int g = t >> 5;
  int n = blockIdx.x * NB2 + g;
  if (n >= N) n = N - 1;

  float acc = 0.f;
#pragma unroll 4
  for (int k = 0; k < 128; ++k)
    acc += x[(size_t)n * 128 + k] * W[k * 32 + c];

  h[(size_t)n * 32 + c] = acc;

  float vs = acc * a_src[c];
  float vd = acc * a_dst[c];
#pragma unroll
  for (int m = 16; m >= 1; m >>= 1) {   // stays within each 32-lane group
    vs += __shfl_xor(vs, m, 64);
    vd += __shfl_xor(vd, m, 64);
  }
  if (c == 0) { asrc[n] = vs; adst[n] = vd; }
}

// Edge aggregation layer 2: 32 lanes per edge (1 head x 32 dims)
__global__ __launch_bounds__(256) void edge2_kernel(
    const int* __restrict__ ei, const float* __restrict__ h,
    const float* __restrict__ asrc, const float* __restrict__ adst,
    float* __restrict__ acc, float* __restrict__ denom, int E, int N)
{
  const int tid  = blockIdx.x * 256 + threadIdx.x;
  const int eidx = tid >> 5;
  const int c    = tid & 31;
  if (eidx >= E + N) return;

  int s, d;
  if (eidx < E) { s = ei[eidx]; d = ei[E + eidx]; }
  else          { s = d = eidx - E; }

  float e = asrc[s] + adst[d];
  e = e > 0.f ? e : NEG * e;
  const float w = expf(e);

  if (c == 0) atomicAdd(&denom[d], w);
  atomicAdd(&acc[(size_t)d * 32 + c], w * h[(size_t)s * 32 + c]);
}

// out = acc/denom + b  (concat=False with H=1 -> mean over 1 head = identity)
__global__ void norm2_kernel(float* __restrict__ out,
                             const float* __restrict__ denom,
                             const float* __restrict__ b, int N)
{
  const int i = blockIdx.x * blockDim.x + threadIdx.x;
  if (i >= N * 32) return;
  const int n = i >> 5, c = i & 31;
  out[i] = out[i] / denom[n] + b[c];
}

// ---------------------------------------------------------------------------
extern "C" void kernel_launch(void* const* d_in, const int* in_sizes, int n_in,
                              void* d_out, int out_size, void* d_ws, size_t ws_size,
                              hipStream_t stream)
{
  const float* x   = (const float*)d_in[0];
  const int*   ei  = (const int*)  d_in[1];
  const float* W1  = (const float*)d_in[2];
  const float* as1 = (const float*)d_in[3];
  const float* ad1 = (const float*)d_in[4];
  const float* b1  = (const float*)d_in[5];
  const float* W2  = (const float*)d_in[6];
  const float* as2 = (const float*)d_in[7];
  const float* ad2 = (const float*)d_in[8];
  const float* b2  = (const float*)d_in[9];

  const int N = in_sizes[0] / 128;
  const int E = in_sizes[1] / 2;

  float* ws     = (float*)d_ws;
  float* h1     = ws;                         // N*128
  float* acc1   = h1     + (size_t)N * 128;   // N*128
  float* asrc1  = acc1   + (size_t)N * 128;   // N*2
  float* adst1  = asrc1  + (size_t)N * 2;     // N*2
  float* denom1 = adst1  + (size_t)N * 2;     // N*2
  float* h2     = denom1 + (size_t)N * 2;     // N*32
  float* asrc2  = h2     + (size_t)N * 32;    // N
  float* adst2  = asrc2  + (size_t)N;         // N
  float* denom2 = adst2  + (size_t)N;         // N
  float* out    = (float*)d_out;              // N*32

  // ---- layer 1 ----
  hipMemsetAsync(acc1,   0, (size_t)N * 128 * sizeof(float), stream);
  hipMemsetAsync(denom1, 0, (size_t)N * 2   * sizeof(float), stream);
  gemm1_kernel<<<(N + NB1 - 1) / NB1, 128, 0, stream>>>(x, W1, as1, ad1,
                                                        h1, asrc1, adst1, N);
  edge1_kernel<<<(E + N + 3) / 4, 256, 0, stream>>>(ei, h1, asrc1, adst1,
                                                    acc1, denom1, E, N);
  norm1_kernel<<<(N * 128 + 255) / 256, 256, 0, stream>>>(acc1, denom1, b1, N);

  // ---- layer 2 ----
  hipMemsetAsync(out,    0, (size_t)N * 32 * sizeof(float), stream);
  hipMemsetAsync(denom2, 0, (size_t)N      * sizeof(float), stream);
  gemm2_kernel<<<(N + NB2 - 1) / NB2, 256, 0, stream>>>(acc1, W2, as2, ad2,
                                                        h2, asrc2, adst2, N);
  edge2_kernel<<<(E + N + 7) / 8, 256, 0, stream>>>(ei, h2, asrc2, adst2,
                                                    out, denom2, E, N);
  norm2_kernel<<<(N * 32 + 255) / 256, 256, 0, stream>>>(out, denom2, b2, N);
}

// Round 2
// 478.098 us; speedup vs baseline: 1.4114x; 1.4114x over previous
//
#include <hip/hip_runtime.h>

#define NEG 0.2f

// ===========================================================================
// Phase A: build dst-sorted CSR (shared by both GAT layers)
// ===========================================================================
__global__ void hist_kernel(const int* __restrict__ ei, int* __restrict__ counts, int E)
{
  const int i = blockIdx.x * 256 + threadIdx.x;
  if (i < E) atomicAdd(&counts[ei[E + i]], 1);
}

// single-block scan over N counts -> offs[0..N], cursor copy
__global__ __launch_bounds__(1024) void scan_kernel(
    const int* __restrict__ counts, int* __restrict__ offs,
    int* __restrict__ cursor, int N)
{
  __shared__ int sums[1024];
  const int t = threadIdx.x;
  const int chunk = (N + 1023) / 1024;
  const int beg = t * chunk;
  const int end = min(beg + chunk, N);

  int s = 0;
  for (int i = beg; i < end; ++i) s += counts[i];
  sums[t] = s;
  __syncthreads();

  for (int off = 1; off < 1024; off <<= 1) {
    int v = (t >= off) ? sums[t - off] : 0;
    __syncthreads();
    if (t >= off) sums[t] += v;
    __syncthreads();
  }

  int run = (t == 0) ? 0 : sums[t - 1];
  for (int i = beg; i < end; ++i) {
    offs[i] = run;
    cursor[i] = run;
    run += counts[i];
  }
  if (t == 1023) offs[N] = run;
}

__global__ void scatter_kernel(const int* __restrict__ ei, int* __restrict__ cursor,
                               int* __restrict__ ssrc, int E)
{
  const int i = blockIdx.x * 256 + threadIdx.x;
  if (i < E) {
    const int d = ei[E + i];
    const int pos = atomicAdd(&cursor[d], 1);
    ssrc[pos] = ei[i];
  }
}

// ===========================================================================
// GEMM1: h1 = x @ W1  (N x 128) @ (128 x 128), fused alpha_src/alpha_dst
// ===========================================================================
constexpr int NB1 = 8;

__global__ __launch_bounds__(128) void gemm1_kernel(
    const float* __restrict__ x, const float* __restrict__ W,
    const float* __restrict__ a_src, const float* __restrict__ a_dst,
    float* __restrict__ h, float* __restrict__ asrc, float* __restrict__ adst,
    int N)
{
  const int j  = threadIdx.x;          // output column 0..127
  const int n0 = blockIdx.x * NB1;

  float acc[NB1];
#pragma unroll
  for (int n = 0; n < NB1; ++n) acc[n] = 0.f;

#pragma unroll 4
  for (int k = 0; k < 128; ++k) {
    float w = W[k * 128 + j];
#pragma unroll
    for (int n = 0; n < NB1; ++n) {
      int nn = n0 + n; if (nn >= N) nn = N - 1;
      acc[n] += x[(size_t)nn * 128 + k] * w;
    }
  }

  const float as = a_src[j];
  const float ad = a_dst[j];
  const int lane = j & 63;
  const int head = j >> 6;

#pragma unroll
  for (int n = 0; n < NB1; ++n) {
    const int nn = n0 + n;
    if (nn >= N) break;
    h[(size_t)nn * 128 + j] = acc[n];
    float vs = acc[n] * as;
    float vd = acc[n] * ad;
#pragma unroll
    for (int m = 32; m >= 1; m >>= 1) {
      vs += __shfl_xor(vs, m, 64);
      vd += __shfl_xor(vd, m, 64);
    }
    if (lane == 0) {
      asrc[nn * 2 + head] = vs;
      adst[nn * 2 + head] = vd;
    }
  }
}

// ===========================================================================
// Layer-1 segment aggregation: one wave per dst node.
// lanes: head0 dim = lane, head1 dim = lane (second 64 cols).
// Fuses softmax-normalize + bias + relu epilogue.
// ===========================================================================
__global__ __launch_bounds__(256) void agg1_kernel(
    const int* __restrict__ offs, const int* __restrict__ ssrc,
    const float* __restrict__ h, const float* __restrict__ asrc,
    const float* __restrict__ adst, const float* __restrict__ b,
    float* __restrict__ out, int N)
{
  const int n = (blockIdx.x * 256 + threadIdx.x) >> 6;
  const int lane = threadIdx.x & 63;
  if (n >= N) return;

  const float ad0 = adst[2 * n];
  const float ad1 = adst[2 * n + 1];

  // self-loop
  float e0 = asrc[2 * n] + ad0;
  float e1 = asrc[2 * n + 1] + ad1;
  e0 = e0 > 0.f ? e0 : NEG * e0;
  e1 = e1 > 0.f ? e1 : NEG * e1;
  float w0 = expf(e0), w1 = expf(e1);
  float den0 = w0, den1 = w1;
  float a0 = w0 * h[(size_t)n * 128 + lane];
  float a1 = w1 * h[(size_t)n * 128 + 64 + lane];

  const int beg = offs[n];
  const int end = offs[n + 1];
  int sNext = (beg < end) ? ssrc[beg] : 0;
  for (int i = beg; i < end; ++i) {
    const int s = sNext;
    sNext = (i + 1 < end) ? ssrc[i + 1] : 0;
    float f0 = asrc[2 * s] + ad0;
    float f1 = asrc[2 * s + 1] + ad1;
    f0 = f0 > 0.f ? f0 : NEG * f0;
    f1 = f1 > 0.f ? f1 : NEG * f1;
    const float v0 = expf(f0);
    const float v1 = expf(f1);
    den0 += v0; den1 += v1;
    a0 += v0 * h[(size_t)s * 128 + lane];
    a1 += v1 * h[(size_t)s * 128 + 64 + lane];
  }

  float r0 = a0 / den0 + b[lane];
  float r1 = a1 / den1 + b[64 + lane];
  out[(size_t)n * 128 + lane]      = r0 > 0.f ? r0 : 0.f;
  out[(size_t)n * 128 + 64 + lane] = r1 > 0.f ? r1 : 0.f;
}

// ===========================================================================
// GEMM2: h2 = out1 @ W2  (N x 128) @ (128 x 32), fused alpha2 (single head)
// ===========================================================================
constexpr int NB2 = 8;

__global__ __launch_bounds__(256) void gemm2_kernel(
    const float* __restrict__ x, const float* __restrict__ W,
    const float* __restrict__ a_src, const float* __restrict__ a_dst,
    float* __restrict__ h, float* __restrict__ asrc, float* __restrict__ adst,
    int N)
{
  const int t = threadIdx.x;
  const int c = t & 31;
  const int g = t >> 5;
  int n = blockIdx.x * NB2 + g;
  if (n >= N) n = N - 1;

  float acc = 0.f;
#pragma unroll 4
  for (int k = 0; k < 128; ++k)
    acc += x[(size_t)n * 128 + k] * W[k * 32 + c];

  h[(size_t)n * 32 + c] = acc;

  float vs = acc * a_src[c];
  float vd = acc * a_dst[c];
#pragma unroll
  for (int m = 16; m >= 1; m >>= 1) {
    vs += __shfl_xor(vs, m, 64);
    vd += __shfl_xor(vd, m, 64);
  }
  if (c == 0) { asrc[n] = vs; adst[n] = vd; }
}

// ===========================================================================
// Layer-2 segment aggregation: one wave per dst node, 2 edges in flight
// (lo half-wave = even edges, hi half-wave = odd edges), C=32.
// Fuses normalize + bias epilogue.
// ===========================================================================
__global__ __launch_bounds__(256) void agg2_kernel(
    const int* __restrict__ offs, const int* __restrict__ ssrc,
    const float* __restrict__ h, const float* __restrict__ asrc,
    const float* __restrict__ adst, const float* __restrict__ b,
    float* __restrict__ out, int N)
{
  const int n = (blockIdx.x * 256 + threadIdx.x) >> 6;
  const int lane = threadIdx.x & 63;
  const int c = lane & 31;
  const int half = lane >> 5;
  if (n >= N) return;

  const float ad = adst[n];
  float den = 0.f, a = 0.f;

  const int beg = offs[n];
  const int end = offs[n + 1];
  for (int i = beg + half; i < end; i += 2) {
    const int s = ssrc[i];
    float f = asrc[s] + ad;
    f = f > 0.f ? f : NEG * f;
    const float w = expf(f);
    den += w;
    a += w * h[(size_t)s * 32 + c];
  }
  if (half == 0) {  // self-loop
    float f = asrc[n] + ad;
    f = f > 0.f ? f : NEG * f;
    const float w = expf(f);
    den += w;
    a += w * h[(size_t)n * 32 + c];
  }

  a   += __shfl_xor(a, 32, 64);
  den += __shfl_xor(den, 32, 64);
  if (half == 0) out[(size_t)n * 32 + c] = a / den + b[c];
}

// ===========================================================================
extern "C" void kernel_launch(void* const* d_in, const int* in_sizes, int n_in,
                              void* d_out, int out_size, void* d_ws, size_t ws_size,
                              hipStream_t stream)
{
  const float* x   = (const float*)d_in[0];
  const int*   ei  = (const int*)  d_in[1];
  const float* W1  = (const float*)d_in[2];
  const float* as1 = (const float*)d_in[3];
  const float* ad1 = (const float*)d_in[4];
  const float* b1  = (const float*)d_in[5];
  const float* W2  = (const float*)d_in[6];
  const float* as2 = (const float*)d_in[7];
  const float* ad2 = (const float*)d_in[8];
  const float* b2  = (const float*)d_in[9];

  const int N = in_sizes[0] / 128;
  const int E = in_sizes[1] / 2;

  // workspace layout
  char* p = (char*)d_ws;
  int* counts = (int*)p;                 p += (size_t)N * 4;
  int* cursor = (int*)p;                 p += (size_t)N * 4;
  int* offs   = (int*)p;                 p += (size_t)(N + 1) * 4;
  int* ssrc   = (int*)p;                 p += (size_t)E * 4;
  float* h1    = (float*)p;              p += (size_t)N * 128 * 4;
  float* out1  = (float*)p;              p += (size_t)N * 128 * 4;
  float* asrc1 = (float*)p;              p += (size_t)N * 2 * 4;
  float* adst1 = (float*)p;              p += (size_t)N * 2 * 4;
  float* h2    = (float*)p;              p += (size_t)N * 32 * 4;
  float* asrc2 = (float*)p;              p += (size_t)N * 4;
  float* adst2 = (float*)p;              p += (size_t)N * 4;
  float* out   = (float*)d_out;          // N*32

  // ---- Phase A: dst-sorted CSR (shared by both layers) ----
  hipMemsetAsync(counts, 0, (size_t)N * 4, stream);
  hist_kernel<<<(E + 255) / 256, 256, 0, stream>>>(ei, counts, E);
  scan_kernel<<<1, 1024, 0, stream>>>(counts, offs, cursor, N);
  scatter_kernel<<<(E + 255) / 256, 256, 0, stream>>>(ei, cursor, ssrc, E);

  // ---- layer 1 ----
  gemm1_kernel<<<(N + NB1 - 1) / NB1, 128, 0, stream>>>(x, W1, as1, ad1,
                                                        h1, asrc1, adst1, N);
  agg1_kernel<<<(N * 64 + 255) / 256, 256, 0, stream>>>(offs, ssrc, h1,
                                                        asrc1, adst1, b1, out1, N);

  // ---- layer 2 ----
  gemm2_kernel<<<(N + NB2 - 1) / NB2, 256, 0, stream>>>(out1, W2, as2, ad2,
                                                        h2, asrc2, adst2, N);
  agg2_kernel<<<(N * 64 + 255) / 256, 256, 0, stream>>>(offs, ssrc, h2,
                                                        asrc2, adst2, b2, out, N);
}

// Round 3
// 357.005 us; speedup vs baseline: 1.8902x; 1.3392x over previous
//
#include <hip/hip_runtime.h>

#define NEG 0.2f

constexpr int SCAN_BLOCKS = 64;

// ===========================================================================
// Phase A: build dst-sorted CSR (shared by both GAT layers)
// ===========================================================================
__global__ void hist_kernel(const int* __restrict__ ei, int* __restrict__ counts, int E)
{
  const int i = blockIdx.x * 256 + threadIdx.x;
  if (i < E) atomicAdd(&counts[ei[E + i]], 1);
}

// per-block partial sums of counts
__global__ __launch_bounds__(256) void scan_a(const int* __restrict__ counts,
                                              int* __restrict__ partial, int N)
{
  const int b = blockIdx.x, t = threadIdx.x;
  const int per_block = (N + SCAN_BLOCKS - 1) / SCAN_BLOCKS;
  const int beg = b * per_block;
  const int end = min(beg + per_block, N);
  int s = 0;
  for (int i = beg + t; i < end; i += 256) s += counts[i];
#pragma unroll
  for (int m = 32; m >= 1; m >>= 1) s += __shfl_xor(s, m, 64);
  __shared__ int ws[4];
  if ((t & 63) == 0) ws[t >> 6] = s;
  __syncthreads();
  if (t == 0) partial[b] = ws[0] + ws[1] + ws[2] + ws[3];
}

// per-block scan: base from partials, block-local LDS scan, write offs+cursor
__global__ __launch_bounds__(256) void scan_c(const int* __restrict__ counts,
                                              const int* __restrict__ partial,
                                              int* __restrict__ offs,
                                              int* __restrict__ cursor, int N)
{
  const int b = blockIdx.x, t = threadIdx.x;
  const int per_block = (N + SCAN_BLOCKS - 1) / SCAN_BLOCKS;
  const int per_thread = (per_block + 255) / 256;
  const int beg = b * per_block;
  const int end = min(beg + per_block, N);

  int base = 0;
  for (int i = 0; i < SCAN_BLOCKS; ++i)
    if (i < b) base += partial[i];

  const int tbeg = beg + t * per_thread;
  const int tend = min(tbeg + per_thread, end);
  int tsum = 0;
  for (int i = tbeg; i < tend; ++i) tsum += counts[i];

  __shared__ int sums[256];
  sums[t] = tsum;
  __syncthreads();
  for (int off = 1; off < 256; off <<= 1) {
    int v = (t >= off) ? sums[t - off] : 0;
    __syncthreads();
    if (t >= off) sums[t] += v;
    __syncthreads();
  }
  int run = base + (t ? sums[t - 1] : 0);
  for (int i = tbeg; i < tend; ++i) {
    offs[i] = run;
    cursor[i] = run;
    run += counts[i];
  }
  if (b == SCAN_BLOCKS - 1 && t == 255) offs[N] = base + sums[255];
}

__global__ void scatter_kernel(const int* __restrict__ ei, int* __restrict__ cursor,
                               int* __restrict__ ssrc, int E)
{
  const int i = blockIdx.x * 256 + threadIdx.x;
  if (i < E) {
    const int d = ei[E + i];
    const int pos = atomicAdd(&cursor[d], 1);
    ssrc[pos] = ei[i];
  }
}

// ===========================================================================
// GEMM1: h1 = x @ W1  (N x 128) @ (128 x 128), fused alpha_src/alpha_dst.
// 256 thr = 8 groups x 32 lanes; lane quad c4 covers 4 cols; group owns 8 nodes.
// ===========================================================================
__global__ __launch_bounds__(256) void gemm1_kernel(
    const float* __restrict__ x, const float* __restrict__ W,
    const float* __restrict__ a_src, const float* __restrict__ a_dst,
    float* __restrict__ h, float* __restrict__ asrc, float* __restrict__ adst,
    int N)
{
  const int t = threadIdx.x;
  const int c4 = (t & 31) << 2;
  const int grp = t >> 5;
  const int n0 = blockIdx.x * 64 + grp * 8;

  int nn[8];
#pragma unroll
  for (int n = 0; n < 8; ++n) { int v = n0 + n; nn[n] = v < N ? v : N - 1; }

  float4 acc[8];
#pragma unroll
  for (int n = 0; n < 8; ++n) acc[n] = make_float4(0.f, 0.f, 0.f, 0.f);

#pragma unroll 2
  for (int k0 = 0; k0 < 128; k0 += 4) {
    const float4 w0 = *(const float4*)(W + (k0 + 0) * 128 + c4);
    const float4 w1 = *(const float4*)(W + (k0 + 1) * 128 + c4);
    const float4 w2 = *(const float4*)(W + (k0 + 2) * 128 + c4);
    const float4 w3 = *(const float4*)(W + (k0 + 3) * 128 + c4);
#pragma unroll
    for (int n = 0; n < 8; ++n) {
      const float4 xv = *(const float4*)(x + (size_t)nn[n] * 128 + k0);
      acc[n].x += xv.x * w0.x + xv.y * w1.x + xv.z * w2.x + xv.w * w3.x;
      acc[n].y += xv.x * w0.y + xv.y * w1.y + xv.z * w2.y + xv.w * w3.y;
      acc[n].z += xv.x * w0.z + xv.y * w1.z + xv.z * w2.z + xv.w * w3.z;
      acc[n].w += xv.x * w0.w + xv.y * w1.w + xv.z * w2.w + xv.w * w3.w;
    }
  }

  const float4 avs = *(const float4*)(a_src + c4);
  const float4 avd = *(const float4*)(a_dst + c4);
  const int head = (t >> 4) & 1;   // lanes 0-15 of group: head0; 16-31: head1

#pragma unroll
  for (int n = 0; n < 8; ++n) {
    *(float4*)(h + (size_t)nn[n] * 128 + c4) = acc[n];
    float vs = acc[n].x * avs.x + acc[n].y * avs.y + acc[n].z * avs.z + acc[n].w * avs.w;
    float vd = acc[n].x * avd.x + acc[n].y * avd.y + acc[n].z * avd.z + acc[n].w * avd.w;
#pragma unroll
    for (int m = 1; m <= 8; m <<= 1) {
      vs += __shfl_xor(vs, m, 64);
      vd += __shfl_xor(vd, m, 64);
    }
    if ((t & 15) == 0) {
      asrc[nn[n] * 2 + head] = vs;
      adst[nn[n] * 2 + head] = vd;
    }
  }
}

// ===========================================================================
// Layer-1 segment aggregation: one wave per dst node (2 heads x 64 dims).
// ===========================================================================
__global__ __launch_bounds__(256) void agg1_kernel(
    const int* __restrict__ offs, const int* __restrict__ ssrc,
    const float* __restrict__ h, const float* __restrict__ asrc,
    const float* __restrict__ adst, const float* __restrict__ b,
    float* __restrict__ out, int N)
{
  const int n = (blockIdx.x * 256 + threadIdx.x) >> 6;
  const int lane = threadIdx.x & 63;
  if (n >= N) return;

  const float ad0 = adst[2 * n];
  const float ad1 = adst[2 * n + 1];

  float e0 = asrc[2 * n] + ad0;
  float e1 = asrc[2 * n + 1] + ad1;
  e0 = e0 > 0.f ? e0 : NEG * e0;
  e1 = e1 > 0.f ? e1 : NEG * e1;
  float w0 = expf(e0), w1 = expf(e1);
  float den0 = w0, den1 = w1;
  float a0 = w0 * h[(size_t)n * 128 + lane];
  float a1 = w1 * h[(size_t)n * 128 + 64 + lane];

  const int beg = offs[n];
  const int end = offs[n + 1];
  int sNext = (beg < end) ? ssrc[beg] : 0;
  for (int i = beg; i < end; ++i) {
    const int s = sNext;
    sNext = (i + 1 < end) ? ssrc[i + 1] : 0;
    float f0 = asrc[2 * s] + ad0;
    float f1 = asrc[2 * s + 1] + ad1;
    f0 = f0 > 0.f ? f0 : NEG * f0;
    f1 = f1 > 0.f ? f1 : NEG * f1;
    const float v0 = expf(f0);
    const float v1 = expf(f1);
    den0 += v0; den1 += v1;
    a0 += v0 * h[(size_t)s * 128 + lane];
    a1 += v1 * h[(size_t)s * 128 + 64 + lane];
  }

  float r0 = a0 / den0 + b[lane];
  float r1 = a1 / den1 + b[64 + lane];
  out[(size_t)n * 128 + lane]      = r0 > 0.f ? r0 : 0.f;
  out[(size_t)n * 128 + 64 + lane] = r1 > 0.f ? r1 : 0.f;
}

// ===========================================================================
// GEMM2: h2 = out1 @ W2  (N x 128) @ (128 x 32), fused alpha2 (single head).
// 256 thr = 32 groups x 8 lanes; lane quad covers 4 of 32 cols; group owns 2 nodes.
// ===========================================================================
__global__ __launch_bounds__(256) void gemm2_kernel(
    const float* __restrict__ x, const float* __restrict__ W,
    const float* __restrict__ a_src, const float* __restrict__ a_dst,
    float* __restrict__ h, float* __restrict__ asrc, float* __restrict__ adst,
    int N)
{
  const int t = threadIdx.x;
  const int c4 = (t & 7) << 2;
  const int grp = t >> 3;
  const int n0 = blockIdx.x * 64 + grp * 2;

  int nn[2];
#pragma unroll
  for (int n = 0; n < 2; ++n) { int v = n0 + n; nn[n] = v < N ? v : N - 1; }

  float4 acc[2];
#pragma unroll
  for (int n = 0; n < 2; ++n) acc[n] = make_float4(0.f, 0.f, 0.f, 0.f);

#pragma unroll 2
  for (int k0 = 0; k0 < 128; k0 += 4) {
    const float4 w0 = *(const float4*)(W + (k0 + 0) * 32 + c4);
    const float4 w1 = *(const float4*)(W + (k0 + 1) * 32 + c4);
    const float4 w2 = *(const float4*)(W + (k0 + 2) * 32 + c4);
    const float4 w3 = *(const float4*)(W + (k0 + 3) * 32 + c4);
#pragma unroll
    for (int n = 0; n < 2; ++n) {
      const float4 xv = *(const float4*)(x + (size_t)nn[n] * 128 + k0);
      acc[n].x += xv.x * w0.x + xv.y * w1.x + xv.z * w2.x + xv.w * w3.x;
      acc[n].y += xv.x * w0.y + xv.y * w1.y + xv.z * w2.y + xv.w * w3.y;
      acc[n].z += xv.x * w0.z + xv.y * w1.z + xv.z * w2.z + xv.w * w3.z;
      acc[n].w += xv.x * w0.w + xv.y * w1.w + xv.z * w2.w + xv.w * w3.w;
    }
  }

  const float4 avs = *(const float4*)(a_src + c4);
  const float4 avd = *(const float4*)(a_dst + c4);

#pragma unroll
  for (int n = 0; n < 2; ++n) {
    *(float4*)(h + (size_t)nn[n] * 32 + c4) = acc[n];
    float vs = acc[n].x * avs.x + acc[n].y * avs.y + acc[n].z * avs.z + acc[n].w * avs.w;
    float vd = acc[n].x * avd.x + acc[n].y * avd.y + acc[n].z * avd.z + acc[n].w * avd.w;
#pragma unroll
    for (int m = 1; m <= 4; m <<= 1) {
      vs += __shfl_xor(vs, m, 64);
      vd += __shfl_xor(vd, m, 64);
    }
    if ((t & 7) == 0) {
      asrc[nn[n]] = vs;
      adst[nn[n]] = vd;
    }
  }
}

// ===========================================================================
// Layer-2 segment aggregation: one wave per dst node, 2 edges in flight.
// ===========================================================================
__global__ __launch_bounds__(256) void agg2_kernel(
    const int* __restrict__ offs, const int* __restrict__ ssrc,
    const float* __restrict__ h, const float* __restrict__ asrc,
    const float* __restrict__ adst, const float* __restrict__ b,
    float* __restrict__ out, int N)
{
  const int n = (blockIdx.x * 256 + threadIdx.x) >> 6;
  const int lane = threadIdx.x & 63;
  const int c = lane & 31;
  const int half = lane >> 5;
  if (n >= N) return;

  const float ad = adst[n];
  float den = 0.f, a = 0.f;

  const int beg = offs[n];
  const int end = offs[n + 1];
  for (int i = beg + half; i < end; i += 2) {
    const int s = ssrc[i];
    float f = asrc[s] + ad;
    f = f > 0.f ? f : NEG * f;
    const float w = expf(f);
    den += w;
    a += w * h[(size_t)s * 32 + c];
  }
  if (half == 0) {  // self-loop
    float f = asrc[n] + ad;
    f = f > 0.f ? f : NEG * f;
    const float w = expf(f);
    den += w;
    a += w * h[(size_t)n * 32 + c];
  }

  a   += __shfl_xor(a, 32, 64);
  den += __shfl_xor(den, 32, 64);
  if (half == 0) out[(size_t)n * 32 + c] = a / den + b[c];
}

// ===========================================================================
extern "C" void kernel_launch(void* const* d_in, const int* in_sizes, int n_in,
                              void* d_out, int out_size, void* d_ws, size_t ws_size,
                              hipStream_t stream)
{
  const float* x   = (const float*)d_in[0];
  const int*   ei  = (const int*)  d_in[1];
  const float* W1  = (const float*)d_in[2];
  const float* as1 = (const float*)d_in[3];
  const float* ad1 = (const float*)d_in[4];
  const float* b1  = (const float*)d_in[5];
  const float* W2  = (const float*)d_in[6];
  const float* as2 = (const float*)d_in[7];
  const float* ad2 = (const float*)d_in[8];
  const float* b2  = (const float*)d_in[9];

  const int N = in_sizes[0] / 128;
  const int E = in_sizes[1] / 2;

  // workspace layout
  char* p = (char*)d_ws;
  int* counts  = (int*)p;                p += (size_t)N * 4;
  int* cursor  = (int*)p;                p += (size_t)N * 4;
  int* offs    = (int*)p;                p += (size_t)(N + 1) * 4;
  int* partial = (int*)p;                p += (size_t)SCAN_BLOCKS * 4;
  int* ssrc    = (int*)p;                p += (size_t)E * 4;
  float* h1    = (float*)p;              p += (size_t)N * 128 * 4;
  float* out1  = (float*)p;              p += (size_t)N * 128 * 4;
  float* asrc1 = (float*)p;              p += (size_t)N * 2 * 4;
  float* adst1 = (float*)p;              p += (size_t)N * 2 * 4;
  float* h2    = (float*)p;              p += (size_t)N * 32 * 4;
  float* asrc2 = (float*)p;              p += (size_t)N * 4;
  float* adst2 = (float*)p;              p += (size_t)N * 4;
  float* out   = (float*)d_out;          // N*32

  // ---- Phase A: dst-sorted CSR ----
  hipMemsetAsync(counts, 0, (size_t)N * 4, stream);
  hist_kernel<<<(E + 255) / 256, 256, 0, stream>>>(ei, counts, E);
  scan_a<<<SCAN_BLOCKS, 256, 0, stream>>>(counts, partial, N);
  scan_c<<<SCAN_BLOCKS, 256, 0, stream>>>(counts, partial, offs, cursor, N);
  scatter_kernel<<<(E + 255) / 256, 256, 0, stream>>>(ei, cursor, ssrc, E);

  // ---- layer 1 ----
  gemm1_kernel<<<(N + 63) / 64, 256, 0, stream>>>(x, W1, as1, ad1,
                                                  h1, asrc1, adst1, N);
  agg1_kernel<<<(N * 64 + 255) / 256, 256, 0, stream>>>(offs, ssrc, h1,
                                                        asrc1, adst1, b1, out1, N);

  // ---- layer 2 ----
  gemm2_kernel<<<(N + 63) / 64, 256, 0, stream>>>(out1, W2, as2, ad2,
                                                  h2, asrc2, adst2, N);
  agg2_kernel<<<(N * 64 + 255) / 256, 256, 0, stream>>>(offs, ssrc, h2,
                                                        asrc2, adst2, b2, out, N);
}

// Round 4
// 322.391 us; speedup vs baseline: 2.0931x; 1.1074x over previous
//
#include <hip/hip_runtime.h>

#define NEG 0.2f

constexpr int SCAN_BLOCKS = 64;

// ===========================================================================
// Phase A: build dst-sorted CSR (shared by both GAT layers)
// ===========================================================================
__global__ void hist_kernel(const int* __restrict__ ei, int* __restrict__ counts, int E)
{
  const int i = blockIdx.x * 256 + threadIdx.x;
  if (i < E) atomicAdd(&counts[ei[E + i]], 1);
}

// per-block partial sums of counts
__global__ __launch_bounds__(256) void scan_a(const int* __restrict__ counts,
                                              int* __restrict__ partial, int N)
{
  const int b = blockIdx.x, t = threadIdx.x;
  const int per_block = (N + SCAN_BLOCKS - 1) / SCAN_BLOCKS;
  const int beg = b * per_block;
  const int end = min(beg + per_block, N);
  int s = 0;
  for (int i = beg + t; i < end; i += 256) s += counts[i];
#pragma unroll
  for (int m = 32; m >= 1; m >>= 1) s += __shfl_xor(s, m, 64);
  __shared__ int ws[4];
  if ((t & 63) == 0) ws[t >> 6] = s;
  __syncthreads();
  if (t == 0) partial[b] = ws[0] + ws[1] + ws[2] + ws[3];
}

// per-block scan: base from partials, block-local LDS scan, write offs+cursor
__global__ __launch_bounds__(256) void scan_c(const int* __restrict__ counts,
                                              const int* __restrict__ partial,
                                              int* __restrict__ offs,
                                              int* __restrict__ cursor, int N)
{
  const int b = blockIdx.x, t = threadIdx.x;
  const int per_block = (N + SCAN_BLOCKS - 1) / SCAN_BLOCKS;
  const int per_thread = (per_block + 255) / 256;
  const int beg = b * per_block;
  const int end = min(beg + per_block, N);

  int base = 0;
  for (int i = 0; i < SCAN_BLOCKS; ++i)
    if (i < b) base += partial[i];

  const int tbeg = beg + t * per_thread;
  const int tend = min(tbeg + per_thread, end);
  int tsum = 0;
  for (int i = tbeg; i < tend; ++i) tsum += counts[i];

  __shared__ int sums[256];
  sums[t] = tsum;
  __syncthreads();
  for (int off = 1; off < 256; off <<= 1) {
    int v = (t >= off) ? sums[t - off] : 0;
    __syncthreads();
    if (t >= off) sums[t] += v;
    __syncthreads();
  }
  int run = base + (t ? sums[t - 1] : 0);
  for (int i = tbeg; i < tend; ++i) {
    offs[i] = run;
    cursor[i] = run;
    run += counts[i];
  }
  if (b == SCAN_BLOCKS - 1 && t == 255) offs[N] = base + sums[255];
}

__global__ void scatter_kernel(const int* __restrict__ ei, int* __restrict__ cursor,
                               int* __restrict__ ssrc, int E)
{
  const int i = blockIdx.x * 256 + threadIdx.x;
  if (i < E) {
    const int d = ei[E + i];
    const int pos = atomicAdd(&cursor[d], 1);
    ssrc[pos] = ei[i];
  }
}

// ===========================================================================
// GEMM1: h1 = x @ W1  (N x 128) @ (128 x 128), fused alpha_src/alpha_dst.
// 256 thr = 8 groups x 32 lanes; lane quad c4 covers 4 cols; group owns 8 nodes.
// ===========================================================================
__global__ __launch_bounds__(256) void gemm1_kernel(
    const float* __restrict__ x, const float* __restrict__ W,
    const float* __restrict__ a_src, const float* __restrict__ a_dst,
    float* __restrict__ h, float* __restrict__ asrc, float* __restrict__ adst,
    int N)
{
  const int t = threadIdx.x;
  const int c4 = (t & 31) << 2;
  const int grp = t >> 5;
  const int n0 = blockIdx.x * 64 + grp * 8;

  int nn[8];
#pragma unroll
  for (int n = 0; n < 8; ++n) { int v = n0 + n; nn[n] = v < N ? v : N - 1; }

  float4 acc[8];
#pragma unroll
  for (int n = 0; n < 8; ++n) acc[n] = make_float4(0.f, 0.f, 0.f, 0.f);

#pragma unroll 2
  for (int k0 = 0; k0 < 128; k0 += 4) {
    const float4 w0 = *(const float4*)(W + (k0 + 0) * 128 + c4);
    const float4 w1 = *(const float4*)(W + (k0 + 1) * 128 + c4);
    const float4 w2 = *(const float4*)(W + (k0 + 2) * 128 + c4);
    const float4 w3 = *(const float4*)(W + (k0 + 3) * 128 + c4);
#pragma unroll
    for (int n = 0; n < 8; ++n) {
      const float4 xv = *(const float4*)(x + (size_t)nn[n] * 128 + k0);
      acc[n].x += xv.x * w0.x + xv.y * w1.x + xv.z * w2.x + xv.w * w3.x;
      acc[n].y += xv.x * w0.y + xv.y * w1.y + xv.z * w2.y + xv.w * w3.y;
      acc[n].z += xv.x * w0.z + xv.y * w1.z + xv.z * w2.z + xv.w * w3.z;
      acc[n].w += xv.x * w0.w + xv.y * w1.w + xv.z * w2.w + xv.w * w3.w;
    }
  }

  const float4 avs = *(const float4*)(a_src + c4);
  const float4 avd = *(const float4*)(a_dst + c4);
  const int head = (t >> 4) & 1;   // lanes 0-15 of group: head0; 16-31: head1

#pragma unroll
  for (int n = 0; n < 8; ++n) {
    *(float4*)(h + (size_t)nn[n] * 128 + c4) = acc[n];
    float vs = acc[n].x * avs.x + acc[n].y * avs.y + acc[n].z * avs.z + acc[n].w * avs.w;
    float vd = acc[n].x * avd.x + acc[n].y * avd.y + acc[n].z * avd.z + acc[n].w * avd.w;
#pragma unroll
    for (int m = 1; m <= 8; m <<= 1) {
      vs += __shfl_xor(vs, m, 64);
      vd += __shfl_xor(vd, m, 64);
    }
    if ((t & 15) == 0) {
      asrc[nn[n] * 2 + head] = vs;
      adst[nn[n] * 2 + head] = vd;
    }
  }
}

// ===========================================================================
// Layer-1 segment aggregation: one wave per dst node.
// 32 lanes cover 128 dims via float4 (lane's head = c>>4); half-waves take
// even/odd edges (2 edges in flight). Fused normalize + bias + relu.
// ===========================================================================
__global__ __launch_bounds__(256) void agg1_kernel(
    const int* __restrict__ offs, const int* __restrict__ ssrc,
    const float* __restrict__ h, const float* __restrict__ asrc,
    const float* __restrict__ adst, const float* __restrict__ b,
    float* __restrict__ out, int N)
{
  const int n = (blockIdx.x * 256 + threadIdx.x) >> 6;
  const int lane = threadIdx.x & 63;
  const int c = lane & 31;        // col-quad index: dims c*4..c*4+3
  const int half = lane >> 5;     // 0 = even edges, 1 = odd edges
  const int head = c >> 4;        // dims <64 -> head0, else head1
  if (n >= N) return;

  const float2 adv = *(const float2*)(adst + 2 * n);

  float4 a = make_float4(0.f, 0.f, 0.f, 0.f);
  float den = 0.f;

  const int beg = offs[n];
  const int end = offs[n + 1];
  for (int i = beg + half; i < end; i += 2) {
    const int s = ssrc[i];
    const float2 asv = *(const float2*)(asrc + 2 * s);
    float e = head ? (asv.y + adv.y) : (asv.x + adv.x);
    e = e > 0.f ? e : NEG * e;
    const float w = __expf(e);
    den += w;
    const float4 hv = *(const float4*)(h + (size_t)s * 128 + c * 4);
    a.x += w * hv.x; a.y += w * hv.y; a.z += w * hv.z; a.w += w * hv.w;
  }

  if (half == 0) {  // self-loop
    const float2 asv = *(const float2*)(asrc + 2 * n);
    float e = head ? (asv.y + adv.y) : (asv.x + adv.x);
    e = e > 0.f ? e : NEG * e;
    const float w = __expf(e);
    den += w;
    const float4 hv = *(const float4*)(h + (size_t)n * 128 + c * 4);
    a.x += w * hv.x; a.y += w * hv.y; a.z += w * hv.z; a.w += w * hv.w;
  }

  // combine the two halves (same c, same head)
  a.x += __shfl_xor(a.x, 32, 64);
  a.y += __shfl_xor(a.y, 32, 64);
  a.z += __shfl_xor(a.z, 32, 64);
  a.w += __shfl_xor(a.w, 32, 64);
  den += __shfl_xor(den, 32, 64);

  if (half == 0) {
    const float4 bv = *(const float4*)(b + c * 4);
    const float inv = 1.f / den;
    float4 r;
    r.x = a.x * inv + bv.x;
    r.y = a.y * inv + bv.y;
    r.z = a.z * inv + bv.z;
    r.w = a.w * inv + bv.w;
    r.x = r.x > 0.f ? r.x : 0.f;
    r.y = r.y > 0.f ? r.y : 0.f;
    r.z = r.z > 0.f ? r.z : 0.f;
    r.w = r.w > 0.f ? r.w : 0.f;
    *(float4*)(out + (size_t)n * 128 + c * 4) = r;
  }
}

// ===========================================================================
// GEMM2: h2 = out1 @ W2  (N x 128) @ (128 x 32), fused alpha2 (single head).
// ===========================================================================
__global__ __launch_bounds__(256) void gemm2_kernel(
    const float* __restrict__ x, const float* __restrict__ W,
    const float* __restrict__ a_src, const float* __restrict__ a_dst,
    float* __restrict__ h, float* __restrict__ asrc, float* __restrict__ adst,
    int N)
{
  const int t = threadIdx.x;
  const int c4 = (t & 7) << 2;
  const int grp = t >> 3;
  const int n0 = blockIdx.x * 64 + grp * 2;

  int nn[2];
#pragma unroll
  for (int n = 0; n < 2; ++n) { int v = n0 + n; nn[n] = v < N ? v : N - 1; }

  float4 acc[2];
#pragma unroll
  for (int n = 0; n < 2; ++n) acc[n] = make_float4(0.f, 0.f, 0.f, 0.f);

#pragma unroll 2
  for (int k0 = 0; k0 < 128; k0 += 4) {
    const float4 w0 = *(const float4*)(W + (k0 + 0) * 32 + c4);
    const float4 w1 = *(const float4*)(W + (k0 + 1) * 32 + c4);
    const float4 w2 = *(const float4*)(W + (k0 + 2) * 32 + c4);
    const float4 w3 = *(const float4*)(W + (k0 + 3) * 32 + c4);
#pragma unroll
    for (int n = 0; n < 2; ++n) {
      const float4 xv = *(const float4*)(x + (size_t)nn[n] * 128 + k0);
      acc[n].x += xv.x * w0.x + xv.y * w1.x + xv.z * w2.x + xv.w * w3.x;
      acc[n].y += xv.x * w0.y + xv.y * w1.y + xv.z * w2.y + xv.w * w3.y;
      acc[n].z += xv.x * w0.z + xv.y * w1.z + xv.z * w2.z + xv.w * w3.z;
      acc[n].w += xv.x * w0.w + xv.y * w1.w + xv.z * w2.w + xv.w * w3.w;
    }
  }

  const float4 avs = *(const float4*)(a_src + c4);
  const float4 avd = *(const float4*)(a_dst + c4);

#pragma unroll
  for (int n = 0; n < 2; ++n) {
    *(float4*)(h + (size_t)nn[n] * 32 + c4) = acc[n];
    float vs = acc[n].x * avs.x + acc[n].y * avs.y + acc[n].z * avs.z + acc[n].w * avs.w;
    float vd = acc[n].x * avd.x + acc[n].y * avd.y + acc[n].z * avd.z + acc[n].w * avd.w;
#pragma unroll
    for (int m = 1; m <= 4; m <<= 1) {
      vs += __shfl_xor(vs, m, 64);
      vd += __shfl_xor(vd, m, 64);
    }
    if ((t & 7) == 0) {
      asrc[nn[n]] = vs;
      adst[nn[n]] = vd;
    }
  }
}

// ===========================================================================
// Layer-2 segment aggregation: one wave per dst node; 8 lanes per edge via
// float4 -> 8 edges in flight. Fused normalize + bias.
// ===========================================================================
__global__ __launch_bounds__(256) void agg2_kernel(
    const int* __restrict__ offs, const int* __restrict__ ssrc,
    const float* __restrict__ h, const float* __restrict__ asrc,
    const float* __restrict__ adst, const float* __restrict__ b,
    float* __restrict__ out, int N)
{
  const int n = (blockIdx.x * 256 + threadIdx.x) >> 6;
  const int lane = threadIdx.x & 63;
  const int g = lane >> 3;          // edge slot 0..7
  const int c4 = (lane & 7) << 2;   // dims c4..c4+3
  if (n >= N) return;

  const float ad = adst[n];
  float4 a = make_float4(0.f, 0.f, 0.f, 0.f);
  float den = 0.f;

  const int beg = offs[n];
  const int end = offs[n + 1];
  for (int i = beg + g; i < end; i += 8) {
    const int s = ssrc[i];
    float f = asrc[s] + ad;
    f = f > 0.f ? f : NEG * f;
    const float w = __expf(f);
    den += w;
    const float4 hv = *(const float4*)(h + (size_t)s * 32 + c4);
    a.x += w * hv.x; a.y += w * hv.y; a.z += w * hv.z; a.w += w * hv.w;
  }
  if (g == 0) {  // self-loop
    float f = asrc[n] + ad;
    f = f > 0.f ? f : NEG * f;
    const float w = __expf(f);
    den += w;
    const float4 hv = *(const float4*)(h + (size_t)n * 32 + c4);
    a.x += w * hv.x; a.y += w * hv.y; a.z += w * hv.z; a.w += w * hv.w;
  }

#pragma unroll
  for (int m = 8; m <= 32; m <<= 1) {
    a.x += __shfl_xor(a.x, m, 64);
    a.y += __shfl_xor(a.y, m, 64);
    a.z += __shfl_xor(a.z, m, 64);
    a.w += __shfl_xor(a.w, m, 64);
    den += __shfl_xor(den, m, 64);
  }

  if (g == 0) {
    const float4 bv = *(const float4*)(b + c4);
    const float inv = 1.f / den;
    float4 r;
    r.x = a.x * inv + bv.x;
    r.y = a.y * inv + bv.y;
    r.z = a.z * inv + bv.z;
    r.w = a.w * inv + bv.w;
    *(float4*)(out + (size_t)n * 32 + c4) = r;
  }
}

// ===========================================================================
extern "C" void kernel_launch(void* const* d_in, const int* in_sizes, int n_in,
                              void* d_out, int out_size, void* d_ws, size_t ws_size,
                              hipStream_t stream)
{
  const float* x   = (const float*)d_in[0];
  const int*   ei  = (const int*)  d_in[1];
  const float* W1  = (const float*)d_in[2];
  const float* as1 = (const float*)d_in[3];
  const float* ad1 = (const float*)d_in[4];
  const float* b1  = (const float*)d_in[5];
  const float* W2  = (const float*)d_in[6];
  const float* as2 = (const float*)d_in[7];
  const float* ad2 = (const float*)d_in[8];
  const float* b2  = (const float*)d_in[9];

  const int N = in_sizes[0] / 128;
  const int E = in_sizes[1] / 2;

  // workspace layout
  char* p = (char*)d_ws;
  int* counts  = (int*)p;                p += (size_t)N * 4;
  int* cursor  = (int*)p;                p += (size_t)N * 4;
  int* offs    = (int*)p;                p += (size_t)(N + 1) * 4;
  int* partial = (int*)p;                p += (size_t)SCAN_BLOCKS * 4;
  int* ssrc    = (int*)p;                p += (size_t)E * 4;
  float* h1    = (float*)p;              p += (size_t)N * 128 * 4;
  float* out1  = (float*)p;              p += (size_t)N * 128 * 4;
  float* asrc1 = (float*)p;              p += (size_t)N * 2 * 4;
  float* adst1 = (float*)p;              p += (size_t)N * 2 * 4;
  float* h2    = (float*)p;              p += (size_t)N * 32 * 4;
  float* asrc2 = (float*)p;              p += (size_t)N * 4;
  float* adst2 = (float*)p;              p += (size_t)N * 4;
  float* out   = (float*)d_out;          // N*32

  // ---- Phase A: dst-sorted CSR ----
  hipMemsetAsync(counts, 0, (size_t)N * 4, stream);
  hist_kernel<<<(E + 255) / 256, 256, 0, stream>>>(ei, counts, E);
  scan_a<<<SCAN_BLOCKS, 256, 0, stream>>>(counts, partial, N);
  scan_c<<<SCAN_BLOCKS, 256, 0, stream>>>(counts, partial, offs, cursor, N);
  scatter_kernel<<<(E + 255) / 256, 256, 0, stream>>>(ei, cursor, ssrc, E);

  // ---- layer 1 ----
  gemm1_kernel<<<(N + 63) / 64, 256, 0, stream>>>(x, W1, as1, ad1,
                                                  h1, asrc1, adst1, N);
  agg1_kernel<<<(N * 64 + 255) / 256, 256, 0, stream>>>(offs, ssrc, h1,
                                                        asrc1, adst1, b1, out1, N);

  // ---- layer 2 ----
  gemm2_kernel<<<(N + 63) / 64, 256, 0, stream>>>(out1, W2, as2, ad2,
                                                  h2, asrc2, adst2, N);
  agg2_kernel<<<(N * 64 + 255) / 256, 256, 0, stream>>>(offs, ssrc, h2,
                                                        asrc2, adst2, b2, out, N);
}

// Round 5
// 311.351 us; speedup vs baseline: 2.1674x; 1.0355x over previous
//
#include <hip/hip_runtime.h>

#define NEG 0.2f

constexpr int SCAN_BLOCKS = 64;

// ===========================================================================
// Phase A: build dst-sorted CSR (shared by both GAT layers)
// ===========================================================================
__global__ void hist_kernel(const int* __restrict__ ei, int* __restrict__ counts, int E)
{
  const int i = blockIdx.x * 256 + threadIdx.x;
  if (i < E) atomicAdd(&counts[ei[E + i]], 1);
}

__global__ __launch_bounds__(256) void scan_a(const int* __restrict__ counts,
                                              int* __restrict__ partial, int N)
{
  const int b = blockIdx.x, t = threadIdx.x;
  const int per_block = (N + SCAN_BLOCKS - 1) / SCAN_BLOCKS;
  const int beg = b * per_block;
  const int end = min(beg + per_block, N);
  int s = 0;
  for (int i = beg + t; i < end; i += 256) s += counts[i];
#pragma unroll
  for (int m = 32; m >= 1; m >>= 1) s += __shfl_xor(s, m, 64);
  __shared__ int ws[4];
  if ((t & 63) == 0) ws[t >> 6] = s;
  __syncthreads();
  if (t == 0) partial[b] = ws[0] + ws[1] + ws[2] + ws[3];
}

__global__ __launch_bounds__(256) void scan_c(const int* __restrict__ counts,
                                              const int* __restrict__ partial,
                                              int* __restrict__ offs,
                                              int* __restrict__ cursor, int N)
{
  const int b = blockIdx.x, t = threadIdx.x;
  const int per_block = (N + SCAN_BLOCKS - 1) / SCAN_BLOCKS;
  const int per_thread = (per_block + 255) / 256;
  const int beg = b * per_block;
  const int end = min(beg + per_block, N);

  int base = 0;
  for (int i = 0; i < SCAN_BLOCKS; ++i)
    if (i < b) base += partial[i];

  const int tbeg = beg + t * per_thread;
  const int tend = min(tbeg + per_thread, end);
  int tsum = 0;
  for (int i = tbeg; i < tend; ++i) tsum += counts[i];

  __shared__ int sums[256];
  sums[t] = tsum;
  __syncthreads();
  for (int off = 1; off < 256; off <<= 1) {
    int v = (t >= off) ? sums[t - off] : 0;
    __syncthreads();
    if (t >= off) sums[t] += v;
    __syncthreads();
  }
  int run = base + (t ? sums[t - 1] : 0);
  for (int i = tbeg; i < tend; ++i) {
    offs[i] = run;
    cursor[i] = run;
    run += counts[i];
  }
  if (b == SCAN_BLOCKS - 1 && t == 255) offs[N] = base + sums[255];
}

// scatter src AND dst so edge-parallel kernels can recover both endpoints
__global__ void scatter_kernel(const int* __restrict__ ei, int* __restrict__ cursor,
                               int* __restrict__ ssrc, int* __restrict__ sdst, int E)
{
  const int i = blockIdx.x * 256 + threadIdx.x;
  if (i < E) {
    const int d = ei[E + i];
    const int pos = atomicAdd(&cursor[d], 1);
    ssrc[pos] = ei[i];
    sdst[pos] = d;
  }
}

// ===========================================================================
// Edge-parallel softmax-weight precompute (removes dependent gathers + exp
// from the segment loops; full edge-level parallelism hides gather latency)
// ===========================================================================
__global__ void edgew1_kernel(const int* __restrict__ ssrc, const int* __restrict__ sdst,
                              const float* __restrict__ asrc, const float* __restrict__ adst,
                              float2* __restrict__ ew, int E)
{
  const int i = blockIdx.x * 256 + threadIdx.x;
  if (i >= E) return;
  const int s = ssrc[i], d = sdst[i];
  const float2 av = *(const float2*)(asrc + 2 * s);
  const float2 dv = *(const float2*)(adst + 2 * d);
  float e0 = av.x + dv.x, e1 = av.y + dv.y;
  e0 = e0 > 0.f ? e0 : NEG * e0;
  e1 = e1 > 0.f ? e1 : NEG * e1;
  ew[i] = make_float2(__expf(e0), __expf(e1));
}

__global__ void edgew2_kernel(const int* __restrict__ ssrc, const int* __restrict__ sdst,
                              const float* __restrict__ asrc, const float* __restrict__ adst,
                              float* __restrict__ ew, int E)
{
  const int i = blockIdx.x * 256 + threadIdx.x;
  if (i >= E) return;
  float e = asrc[ssrc[i]] + adst[sdst[i]];
  e = e > 0.f ? e : NEG * e;
  ew[i] = __expf(e);
}

// ===========================================================================
// GEMM1: h1 = x @ W1  (N x 128) @ (128 x 128), fused alpha_src/alpha_dst.
// ===========================================================================
__global__ __launch_bounds__(256) void gemm1_kernel(
    const float* __restrict__ x, const float* __restrict__ W,
    const float* __restrict__ a_src, const float* __restrict__ a_dst,
    float* __restrict__ h, float* __restrict__ asrc, float* __restrict__ adst,
    int N)
{
  const int t = threadIdx.x;
  const int c4 = (t & 31) << 2;
  const int grp = t >> 5;
  const int n0 = blockIdx.x * 64 + grp * 8;

  int nn[8];
#pragma unroll
  for (int n = 0; n < 8; ++n) { int v = n0 + n; nn[n] = v < N ? v : N - 1; }

  float4 acc[8];
#pragma unroll
  for (int n = 0; n < 8; ++n) acc[n] = make_float4(0.f, 0.f, 0.f, 0.f);

#pragma unroll 2
  for (int k0 = 0; k0 < 128; k0 += 4) {
    const float4 w0 = *(const float4*)(W + (k0 + 0) * 128 + c4);
    const float4 w1 = *(const float4*)(W + (k0 + 1) * 128 + c4);
    const float4 w2 = *(const float4*)(W + (k0 + 2) * 128 + c4);
    const float4 w3 = *(const float4*)(W + (k0 + 3) * 128 + c4);
#pragma unroll
    for (int n = 0; n < 8; ++n) {
      const float4 xv = *(const float4*)(x + (size_t)nn[n] * 128 + k0);
      acc[n].x += xv.x * w0.x + xv.y * w1.x + xv.z * w2.x + xv.w * w3.x;
      acc[n].y += xv.x * w0.y + xv.y * w1.y + xv.z * w2.y + xv.w * w3.y;
      acc[n].z += xv.x * w0.z + xv.y * w1.z + xv.z * w2.z + xv.w * w3.z;
      acc[n].w += xv.x * w0.w + xv.y * w1.w + xv.z * w2.w + xv.w * w3.w;
    }
  }

  const float4 avs = *(const float4*)(a_src + c4);
  const float4 avd = *(const float4*)(a_dst + c4);
  const int head = (t >> 4) & 1;

#pragma unroll
  for (int n = 0; n < 8; ++n) {
    *(float4*)(h + (size_t)nn[n] * 128 + c4) = acc[n];
    float vs = acc[n].x * avs.x + acc[n].y * avs.y + acc[n].z * avs.z + acc[n].w * avs.w;
    float vd = acc[n].x * avd.x + acc[n].y * avd.y + acc[n].z * avd.z + acc[n].w * avd.w;
#pragma unroll
    for (int m = 1; m <= 8; m <<= 1) {
      vs += __shfl_xor(vs, m, 64);
      vd += __shfl_xor(vd, m, 64);
    }
    if ((t & 15) == 0) {
      asrc[nn[n] * 2 + head] = vs;
      adst[nn[n] * 2 + head] = vd;
    }
  }
}

// ===========================================================================
// Layer-1 segment aggregation: one wave per dst node; 32 lanes cover 128 dims
// via float4; halves take even/odd edges; 4 edges per half in flight
// (8 independent h-gathers per wave). Weights precomputed in ew.
// ===========================================================================
__global__ __launch_bounds__(256) void agg1_kernel(
    const int* __restrict__ offs, const int* __restrict__ ssrc,
    const float2* __restrict__ ew,
    const float* __restrict__ h, const float* __restrict__ asrc,
    const float* __restrict__ adst, const float* __restrict__ b,
    float* __restrict__ out, int N)
{
  const int n = (blockIdx.x * 256 + threadIdx.x) >> 6;
  const int lane = threadIdx.x & 63;
  const int c = lane & 31;
  const int half = lane >> 5;
  const int head = c >> 4;
  if (n >= N) return;

  float4 a = make_float4(0.f, 0.f, 0.f, 0.f);
  float den = 0.f;

  const int beg = offs[n];
  const int end = offs[n + 1];

  for (int i0 = beg + half; i0 < end; i0 += 8) {
    const int i1 = i0 + 2, i2 = i0 + 4, i3 = i0 + 6;
    const bool v1 = i1 < end, v2 = i2 < end, v3 = i3 < end;

    const int s0 = ssrc[i0];
    const int s1 = v1 ? ssrc[i1] : s0;
    const int s2 = v2 ? ssrc[i2] : s0;
    const int s3 = v3 ? ssrc[i3] : s0;

    const float2 ww0 = ew[i0];
    const float2 ww1 = v1 ? ew[i1] : make_float2(0.f, 0.f);
    const float2 ww2 = v2 ? ew[i2] : make_float2(0.f, 0.f);
    const float2 ww3 = v3 ? ew[i3] : make_float2(0.f, 0.f);

    const float4 h0 = *(const float4*)(h + (size_t)s0 * 128 + c * 4);
    const float4 h1 = *(const float4*)(h + (size_t)s1 * 128 + c * 4);
    const float4 h2 = *(const float4*)(h + (size_t)s2 * 128 + c * 4);
    const float4 h3 = *(const float4*)(h + (size_t)s3 * 128 + c * 4);

    const float w0 = head ? ww0.y : ww0.x;
    const float w1 = head ? ww1.y : ww1.x;
    const float w2 = head ? ww2.y : ww2.x;
    const float w3 = head ? ww3.y : ww3.x;

    den += (w0 + w1) + (w2 + w3);
    a.x += w0 * h0.x + w1 * h1.x + w2 * h2.x + w3 * h3.x;
    a.y += w0 * h0.y + w1 * h1.y + w2 * h2.y + w3 * h3.y;
    a.z += w0 * h0.z + w1 * h1.z + w2 * h2.z + w3 * h3.z;
    a.w += w0 * h0.w + w1 * h1.w + w2 * h2.w + w3 * h3.w;
  }

  if (half == 0) {  // self-loop
    const float2 asv = *(const float2*)(asrc + 2 * n);
    const float2 adv = *(const float2*)(adst + 2 * n);
    float e = head ? (asv.y + adv.y) : (asv.x + adv.x);
    e = e > 0.f ? e : NEG * e;
    const float w = __expf(e);
    den += w;
    const float4 hv = *(const float4*)(h + (size_t)n * 128 + c * 4);
    a.x += w * hv.x; a.y += w * hv.y; a.z += w * hv.z; a.w += w * hv.w;
  }

  a.x += __shfl_xor(a.x, 32, 64);
  a.y += __shfl_xor(a.y, 32, 64);
  a.z += __shfl_xor(a.z, 32, 64);
  a.w += __shfl_xor(a.w, 32, 64);
  den += __shfl_xor(den, 32, 64);

  if (half == 0) {
    const float4 bv = *(const float4*)(b + c * 4);
    const float inv = 1.f / den;
    float4 r;
    r.x = a.x * inv + bv.x;
    r.y = a.y * inv + bv.y;
    r.z = a.z * inv + bv.z;
    r.w = a.w * inv + bv.w;
    r.x = r.x > 0.f ? r.x : 0.f;
    r.y = r.y > 0.f ? r.y : 0.f;
    r.z = r.z > 0.f ? r.z : 0.f;
    r.w = r.w > 0.f ? r.w : 0.f;
    *(float4*)(out + (size_t)n * 128 + c * 4) = r;
  }
}

// ===========================================================================
// GEMM2: h2 = out1 @ W2  (N x 128) @ (128 x 32), fused alpha2 (single head).
// ===========================================================================
__global__ __launch_bounds__(256) void gemm2_kernel(
    const float* __restrict__ x, const float* __restrict__ W,
    const float* __restrict__ a_src, const float* __restrict__ a_dst,
    float* __restrict__ h, float* __restrict__ asrc, float* __restrict__ adst,
    int N)
{
  const int t = threadIdx.x;
  const int c4 = (t & 7) << 2;
  const int grp = t >> 3;
  const int n0 = blockIdx.x * 64 + grp * 2;

  int nn[2];
#pragma unroll
  for (int n = 0; n < 2; ++n) { int v = n0 + n; nn[n] = v < N ? v : N - 1; }

  float4 acc[2];
#pragma unroll
  for (int n = 0; n < 2; ++n) acc[n] = make_float4(0.f, 0.f, 0.f, 0.f);

#pragma unroll 2
  for (int k0 = 0; k0 < 128; k0 += 4) {
    const float4 w0 = *(const float4*)(W + (k0 + 0) * 32 + c4);
    const float4 w1 = *(const float4*)(W + (k0 + 1) * 32 + c4);
    const float4 w2 = *(const float4*)(W + (k0 + 2) * 32 + c4);
    const float4 w3 = *(const float4*)(W + (k0 + 3) * 32 + c4);
#pragma unroll
    for (int n = 0; n < 2; ++n) {
      const float4 xv = *(const float4*)(x + (size_t)nn[n] * 128 + k0);
      acc[n].x += xv.x * w0.x + xv.y * w1.x + xv.z * w2.x + xv.w * w3.x;
      acc[n].y += xv.x * w0.y + xv.y * w1.y + xv.z * w2.y + xv.w * w3.y;
      acc[n].z += xv.x * w0.z + xv.y * w1.z + xv.z * w2.z + xv.w * w3.z;
      acc[n].w += xv.x * w0.w + xv.y * w1.w + xv.z * w2.w + xv.w * w3.w;
    }
  }

  const float4 avs = *(const float4*)(a_src + c4);
  const float4 avd = *(const float4*)(a_dst + c4);

#pragma unroll
  for (int n = 0; n < 2; ++n) {
    *(float4*)(h + (size_t)nn[n] * 32 + c4) = acc[n];
    float vs = acc[n].x * avs.x + acc[n].y * avs.y + acc[n].z * avs.z + acc[n].w * avs.w;
    float vd = acc[n].x * avd.x + acc[n].y * avd.y + acc[n].z * avd.z + acc[n].w * avd.w;
#pragma unroll
    for (int m = 1; m <= 4; m <<= 1) {
      vs += __shfl_xor(vs, m, 64);
      vd += __shfl_xor(vd, m, 64);
    }
    if ((t & 7) == 0) {
      asrc[nn[n]] = vs;
      adst[nn[n]] = vd;
    }
  }
}

// ===========================================================================
// Layer-2 segment aggregation: one wave per dst node; 8 lanes per edge via
// float4 -> 8 edge slots; unroll 2 -> 16 gathers in flight. Weights in ew.
// ===========================================================================
__global__ __launch_bounds__(256) void agg2_kernel(
    const int* __restrict__ offs, const int* __restrict__ ssrc,
    const float* __restrict__ ew,
    const float* __restrict__ h, const float* __restrict__ asrc,
    const float* __restrict__ adst, const float* __restrict__ b,
    float* __restrict__ out, int N)
{
  const int n = (blockIdx.x * 256 + threadIdx.x) >> 6;
  const int lane = threadIdx.x & 63;
  const int g = lane >> 3;          // edge slot 0..7
  const int c4 = (lane & 7) << 2;   // dims c4..c4+3
  if (n >= N) return;

  float4 a = make_float4(0.f, 0.f, 0.f, 0.f);
  float den = 0.f;

  const int beg = offs[n];
  const int end = offs[n + 1];

  for (int i0 = beg + g; i0 < end; i0 += 16) {
    const int i1 = i0 + 8;
    const bool v1 = i1 < end;

    const int s0 = ssrc[i0];
    const int s1 = v1 ? ssrc[i1] : s0;
    const float w0 = ew[i0];
    const float w1 = v1 ? ew[i1] : 0.f;

    const float4 h0 = *(const float4*)(h + (size_t)s0 * 32 + c4);
    const float4 h1 = *(const float4*)(h + (size_t)s1 * 32 + c4);

    den += w0 + w1;
    a.x += w0 * h0.x + w1 * h1.x;
    a.y += w0 * h0.y + w1 * h1.y;
    a.z += w0 * h0.z + w1 * h1.z;
    a.w += w0 * h0.w + w1 * h1.w;
  }

  if (g == 0) {  // self-loop
    float e = asrc[n] + adst[n];
    e = e > 0.f ? e : NEG * e;
    const float w = __expf(e);
    den += w;
    const float4 hv = *(const float4*)(h + (size_t)n * 32 + c4);
    a.x += w * hv.x; a.y += w * hv.y; a.z += w * hv.z; a.w += w * hv.w;
  }

#pragma unroll
  for (int m = 8; m <= 32; m <<= 1) {
    a.x += __shfl_xor(a.x, m, 64);
    a.y += __shfl_xor(a.y, m, 64);
    a.z += __shfl_xor(a.z, m, 64);
    a.w += __shfl_xor(a.w, m, 64);
    den += __shfl_xor(den, m, 64);
  }

  if (g == 0) {
    const float4 bv = *(const float4*)(b + c4);
    const float inv = 1.f / den;
    float4 r;
    r.x = a.x * inv + bv.x;
    r.y = a.y * inv + bv.y;
    r.z = a.z * inv + bv.z;
    r.w = a.w * inv + bv.w;
    *(float4*)(out + (size_t)n * 32 + c4) = r;
  }
}

// ===========================================================================
extern "C" void kernel_launch(void* const* d_in, const int* in_sizes, int n_in,
                              void* d_out, int out_size, void* d_ws, size_t ws_size,
                              hipStream_t stream)
{
  const float* x   = (const float*)d_in[0];
  const int*   ei  = (const int*)  d_in[1];
  const float* W1  = (const float*)d_in[2];
  const float* as1 = (const float*)d_in[3];
  const float* ad1 = (const float*)d_in[4];
  const float* b1  = (const float*)d_in[5];
  const float* W2  = (const float*)d_in[6];
  const float* as2 = (const float*)d_in[7];
  const float* ad2 = (const float*)d_in[8];
  const float* b2  = (const float*)d_in[9];

  const int N = in_sizes[0] / 128;
  const int E = in_sizes[1] / 2;

  // workspace layout
  char* p = (char*)d_ws;
  int* counts  = (int*)p;                p += (size_t)N * 4;
  int* cursor  = (int*)p;                p += (size_t)N * 4;
  int* offs    = (int*)p;                p += (size_t)(N + 1) * 4;
  int* partial = (int*)p;                p += (size_t)SCAN_BLOCKS * 4;
  int* ssrc    = (int*)p;                p += (size_t)E * 4;
  int* sdst    = (int*)p;                p += (size_t)E * 4;
  float2* ew1  = (float2*)p;             p += (size_t)E * 8;
  float* ew2   = (float*)p;              p += (size_t)E * 4;
  float* h1    = (float*)p;              p += (size_t)N * 128 * 4;
  float* out1  = (float*)p;              p += (size_t)N * 128 * 4;
  float* asrc1 = (float*)p;              p += (size_t)N * 2 * 4;
  float* adst1 = (float*)p;              p += (size_t)N * 2 * 4;
  float* h2    = (float*)p;              p += (size_t)N * 32 * 4;
  float* asrc2 = (float*)p;              p += (size_t)N * 4;
  float* adst2 = (float*)p;              p += (size_t)N * 4;
  float* out   = (float*)d_out;          // N*32

  // ---- Phase A: dst-sorted CSR ----
  hipMemsetAsync(counts, 0, (size_t)N * 4, stream);
  hist_kernel<<<(E + 255) / 256, 256, 0, stream>>>(ei, counts, E);
  scan_a<<<SCAN_BLOCKS, 256, 0, stream>>>(counts, partial, N);
  scan_c<<<SCAN_BLOCKS, 256, 0, stream>>>(counts, partial, offs, cursor, N);
  scatter_kernel<<<(E + 255) / 256, 256, 0, stream>>>(ei, cursor, ssrc, sdst, E);

  // ---- layer 1 ----
  gemm1_kernel<<<(N + 63) / 64, 256, 0, stream>>>(x, W1, as1, ad1,
                                                  h1, asrc1, adst1, N);
  edgew1_kernel<<<(E + 255) / 256, 256, 0, stream>>>(ssrc, sdst, asrc1, adst1, ew1, E);
  agg1_kernel<<<(N * 64 + 255) / 256, 256, 0, stream>>>(offs, ssrc, ew1, h1,
                                                        asrc1, adst1, b1, out1, N);

  // ---- layer 2 ----
  gemm2_kernel<<<(N + 63) / 64, 256, 0, stream>>>(out1, W2, as2, ad2,
                                                  h2, asrc2, adst2, N);
  edgew2_kernel<<<(E + 255) / 256, 256, 0, stream>>>(ssrc, sdst, asrc2, adst2, ew2, E);
  agg2_kernel<<<(N * 64 + 255) / 256, 256, 0, stream>>>(offs, ssrc, ew2, h2,
                                                        asrc2, adst2, b2, out, N);
}